// Round 1
// baseline (27.517 us; speedup 1.0000x reference)
//
#include <hip/hip_runtime.h>

#define HW 16384      // 128*128
#define NCH 128       // channels
#define CCH 8         // channels per block
#define LANG 256
#define NH 128
#define NOP 6

// Per-batch coefficients: coefs[b*12 + 0..5] = gamma[b,k]*wr[k],
// coefs[b*12 + 6..11] = beta[b,k]*wr[k]; coefs[48] = sum(wr); coefs[49] = br.
__global__ __launch_bounds__(128) void coef_kernel(
    const float* __restrict__ lang, const float* __restrict__ Ws,
    const float* __restrict__ bs, const float* __restrict__ Wg,
    const float* __restrict__ bg, const float* __restrict__ Wb,
    const float* __restrict__ bb, const float* __restrict__ Wr,
    const float* __restrict__ br, float* __restrict__ coefs) {
  const int b = blockIdx.x;
  const int j = threadIdx.x;
  __shared__ float actv[NH];

  // actv[b,j] = bs[j] + sum_i lang[b,i] * Ws[j,i]
  const float* l = lang + b * LANG;
  const float* w = Ws + j * LANG;
  float a = bs[j];
  #pragma unroll 4
  for (int i = 0; i < LANG; ++i) a += l[i] * w[i];
  actv[j] = a;
  __syncthreads();

  if (j < 2 * NOP) {
    const int k = j % NOP, sel = j / NOP;  // sel=0 -> gamma, 1 -> beta
    const float* W = (sel ? Wb : Wg) + k * NH;
    float v = sel ? bb[k] : bg[k];
    for (int i = 0; i < NH; ++i) v += actv[i] * W[i];
    coefs[b * 12 + sel * NOP + k] = v * Wr[k];
  }
  if (b == 0 && j == 2 * NOP) {
    float s = 0.f;
    for (int k = 0; k < NOP; ++k) s += Wr[k];
    coefs[48] = s;
    coefs[49] = br[0];
  }
}

__global__ __launch_bounds__(256) void apply_kernel(
    const float* __restrict__ x, const float* __restrict__ sem,
    const float* __restrict__ coefs, float* __restrict__ out) {
  const int b = blockIdx.z;
  const int cbase = blockIdx.y * CCH;
  const int pix = (blockIdx.x * blockDim.x + threadIdx.x) * 4;

  const float* gk = coefs + b * 12;
  const float wrsum = coefs[48];
  const float brv = coefs[49];

  float4 scale = make_float4(wrsum, wrsum, wrsum, wrsum);
  float4 shift = make_float4(brv, brv, brv, brv);

  // sem planes 2..7 of input_semantics (B,8,H,W)
  const float* semb = sem + ((size_t)b * 8 + 2) * HW + pix;
  #pragma unroll
  for (int k = 0; k < NOP; ++k) {
    float4 s = *(const float4*)(semb + (size_t)k * HW);
    const float g = gk[k], be = gk[NOP + k];
    scale.x += g * s.x;  scale.y += g * s.y;
    scale.z += g * s.z;  scale.w += g * s.w;
    shift.x += be * s.x; shift.y += be * s.y;
    shift.z += be * s.z; shift.w += be * s.w;
  }

  const size_t base = ((size_t)b * NCH + cbase) * HW + pix;
  const float* xb = x + base;
  float* ob = out + base;
  #pragma unroll
  for (int c = 0; c < CCH; ++c) {
    float4 v = *(const float4*)(xb + (size_t)c * HW);
    float4 r;
    r.x = v.x * scale.x + shift.x;
    r.y = v.y * scale.y + shift.y;
    r.z = v.z * scale.z + shift.z;
    r.w = v.w * scale.w + shift.w;
    *(float4*)(ob + (size_t)c * HW) = r;
  }
}

extern "C" void kernel_launch(void* const* d_in, const int* in_sizes, int n_in,
                              void* d_out, int out_size, void* d_ws, size_t ws_size,
                              hipStream_t stream) {
  const float* x    = (const float*)d_in[0];
  const float* lang = (const float*)d_in[1];
  const float* sem  = (const float*)d_in[2];
  const float* Ws   = (const float*)d_in[3];
  const float* bs   = (const float*)d_in[4];
  const float* Wg   = (const float*)d_in[5];
  const float* bg   = (const float*)d_in[6];
  const float* Wb   = (const float*)d_in[7];
  const float* bb   = (const float*)d_in[8];
  const float* Wr   = (const float*)d_in[9];
  const float* br   = (const float*)d_in[10];
  float* out = (float*)d_out;
  float* coefs = (float*)d_ws;  // 50 floats

  coef_kernel<<<dim3(4), dim3(128), 0, stream>>>(lang, Ws, bs, Wg, bg, Wb, bb,
                                                 Wr, br, coefs);

  dim3 grid(HW / (256 * 4), NCH / CCH, 4);  // (16, 16, 4)
  apply_kernel<<<grid, dim3(256), 0, stream>>>(x, sem, coefs, out);
}